// Round 2
// baseline (220.014 us; speedup 1.0000x reference)
//
#include <hip/hip_runtime.h>

// Problem constants
// B=32, T_IN=12, H=64, W=64, C_IN=4, T_OUT=12, C_OUT=4, O=48, K=8, S=4
// NH=NW=15, L=225. DEC_K=25, p=12 -> trend[t] = A + t*D (affine in t).

// Packed weights: PW[(s*48 + o)*64 + k], s = i*8 + j, k in [0,57):
//   k=t*4+c  (0..47): w_s[o,t,c,i,j]
//   k=48+c          : W0[o,c,i,j] = sum_t (w_t - w_s)
//   k=52+c          : W1[o,c,i,j] = sum_t t*(w_t - w_s)
//   k=56            : b_s[o,i,j] + b_t[o,i,j]
// One block per o (48 blocks), 64 threads = s. All w reads coalesced
// (s is the innermost, contiguous dim of (O,T,C,K,K)).
__global__ __launch_bounds__(64) void pack_weights(const float* __restrict__ w_s,
                                                   const float* __restrict__ b_s,
                                                   const float* __restrict__ w_t,
                                                   const float* __restrict__ b_t,
                                                   float* __restrict__ PW) {
    int o = blockIdx.x;   // 0..47
    int s = threadIdx.x;  // 0..63
    float* dst = PW + (size_t)(s * 48 + o) * 64;
    float w0[4] = {0.f, 0.f, 0.f, 0.f};
    float w1[4] = {0.f, 0.f, 0.f, 0.f};
#pragma unroll
    for (int t = 0; t < 12; ++t) {
#pragma unroll
        for (int c = 0; c < 4; ++c) {
            int wi = ((o * 12 + t) * 4 + c) * 64 + s;
            float ws = w_s[wi];
            float wt = w_t[wi];
            dst[t * 4 + c] = ws;
            float d = wt - ws;
            w0[c] += d;
            w1[c] += (float)t * d;
        }
    }
#pragma unroll
    for (int c = 0; c < 4; ++c) {
        dst[48 + c] = w0[c];
        dst[52 + c] = w1[c];
    }
    dst[56] = b_s[o * 64 + s] + b_t[o * 64 + s];
}

// Grid: 32 b x 16 residue classes x 4 to-groups = 2048 blocks
// (8 blocks/CU x 4 waves = 32 waves/CU -> 100% occupancy at <=64 VGPR).
// Each block: 256 threads = 16x16 pixels of one residue class, 3 of the 12
// output timesteps. Thread: load x[12][4] once (float4/t), build
// X[57] = [x(t,c), A(c), D(c), 1], dot against <=4 wave-uniform (scalar-load)
// packed weight slices per to.
__global__ __launch_bounds__(256, 8) void dlinear_main(const float* __restrict__ x,
                                                       const float* __restrict__ PW,
                                                       float* __restrict__ out) {
    int tid = threadIdx.x;
    int hh = tid >> 4;  // 0..15
    int ww = tid & 15;  // 0..15
    int tg = blockIdx.x & 3;          // to-group: to = 3*tg .. 3*tg+2
    int cls = (blockIdx.x >> 2) & 15; // residue class
    int bb = blockIdx.x >> 6;         // batch
    int rh = cls >> 2;  // h residue 0..3
    int rw = cls & 3;   // w residue 0..3
    int h = 4 * hh + rh;
    int w = 4 * ww + rw;

    // x layout (B,T,H,W,C): float4 index = (b*12+t)*4096 + h*64 + w
    const float4* xb = (const float4*)x + (size_t)bb * 12 * 4096 + h * 64 + w;

    float X[57];
    float sx = 0.f, sy = 0.f, sz = 0.f, sw = 0.f;
#pragma unroll
    for (int t = 0; t < 12; ++t) {
        float4 v = xb[t * 4096];
        X[t * 4 + 0] = v.x;
        X[t * 4 + 1] = v.y;
        X[t * 4 + 2] = v.z;
        X[t * 4 + 3] = v.w;
        sx += v.x; sy += v.y; sz += v.z; sw += v.w;
    }
    const float inv25 = 1.0f / 25.0f;
    {
        float S[4] = {sx, sy, sz, sw};
#pragma unroll
        for (int c = 0; c < 4; ++c) {
            float x0 = X[c], x11 = X[44 + c];
            X[48 + c] = (S[c] + 12.f * x0 + x11) * inv25;  // A
            X[52 + c] = (x11 - x0) * inv25;                // D
        }
    }
    X[56] = 1.0f;

    // combo validity: di=0 needs hh<=14; di=1 needs hh>=1 (same for j/ww)
    bool iv[2] = {hh <= 14, hh >= 1};
    bool jv[2] = {ww <= 14, ww >= 1};

    float4* ob = (float4*)out + (size_t)bb * 12 * 4096 + h * 64 + w;

#pragma unroll
    for (int tt = 0; tt < 3; ++tt) {
        int to = 3 * tg + tt;
        float rx = 0.f, ry = 0.f, rz = 0.f, rw4 = 0.f;
#pragma unroll
        for (int di = 0; di < 2; ++di) {
#pragma unroll
            for (int dj = 0; dj < 2; ++dj) {
                if (iv[di] && jv[dj]) {
                    int s = (rh + 4 * di) * 8 + (rw + 4 * dj);
                    const float* wb = PW + (size_t)(s * 48 + to * 4) * 64;
                    float a0 = 0.f, a1 = 0.f, a2 = 0.f, a3 = 0.f;
#pragma unroll
                    for (int k = 0; k < 57; ++k) {
                        float xv = X[k];
                        a0 += xv * wb[k];
                        a1 += xv * wb[64 + k];
                        a2 += xv * wb[128 + k];
                        a3 += xv * wb[192 + k];
                    }
                    rx += a0; ry += a1; rz += a2; rw4 += a3;
                }
            }
        }
        float4 r;
        r.x = rx; r.y = ry; r.z = rz; r.w = rw4;
        ob[to * 4096] = r;
    }
}

extern "C" void kernel_launch(void* const* d_in, const int* in_sizes, int n_in,
                              void* d_out, int out_size, void* d_ws, size_t ws_size,
                              hipStream_t stream) {
    const float* x = (const float*)d_in[0];
    const float* w_s = (const float*)d_in[1];
    const float* b_s = (const float*)d_in[2];
    const float* w_t = (const float*)d_in[3];
    const float* b_t = (const float*)d_in[4];
    float* out = (float*)d_out;
    float* PW = (float*)d_ws;  // needs 48*64*64*4 = 786432 bytes

    pack_weights<<<48, 64, 0, stream>>>(w_s, b_s, w_t, b_t, PW);
    dlinear_main<<<32 * 16 * 4, 256, 0, stream>>>(x, PW, out);
}

// Round 3
// 149.278 us; speedup vs baseline: 1.4739x; 1.4739x over previous
//
#include <hip/hip_runtime.h>

// Problem constants
// B=32, T_IN=12, H=64, W=64, C_IN=4, T_OUT=12, C_OUT=4, O=48, K=8, S=4
// NH=NW=15, L=225. DEC_K=25, p=12 -> trend[t] = A + t*D (affine in t).

// Packed weights: PW[(s*48 + o)*64 + k], s = i*8 + j, k in [0,57):
//   k=t*4+c  (0..47): w_s[o,t,c,i,j]
//   k=48+c          : W0[o,c,i,j] = sum_t (w_t - w_s)
//   k=52+c          : W1[o,c,i,j] = sum_t t*(w_t - w_s)
//   k=56            : b_s[o,i,j] + b_t[o,i,j]
// One block per o (48 blocks), 64 threads = s. All w reads coalesced
// (s is the innermost, contiguous dim of (O,T,C,K,K)).
__global__ __launch_bounds__(64) void pack_weights(const float* __restrict__ w_s,
                                                   const float* __restrict__ b_s,
                                                   const float* __restrict__ w_t,
                                                   const float* __restrict__ b_t,
                                                   float* __restrict__ PW) {
    int o = blockIdx.x;   // 0..47
    int s = threadIdx.x;  // 0..63
    float* dst = PW + (size_t)(s * 48 + o) * 64;
    float w0[4] = {0.f, 0.f, 0.f, 0.f};
    float w1[4] = {0.f, 0.f, 0.f, 0.f};
#pragma unroll
    for (int t = 0; t < 12; ++t) {
#pragma unroll
        for (int c = 0; c < 4; ++c) {
            int wi = ((o * 12 + t) * 4 + c) * 64 + s;
            float ws = w_s[wi];
            float wt = w_t[wi];
            dst[t * 4 + c] = ws;
            float d = wt - ws;
            w0[c] += d;
            w1[c] += (float)t * d;
        }
    }
#pragma unroll
    for (int c = 0; c < 4; ++c) {
        dst[48 + c] = w0[c];
        dst[52 + c] = w1[c];
    }
    dst[56] = b_s[o * 64 + s] + b_t[o * 64 + s];
}

// Grid: 32 b x 16 residue classes x 2 to-groups = 1024 blocks = 4 blocks/CU.
// __launch_bounds__(256,4): VGPR cap 128 -> no spill (natural ~80), 16
// waves/CU resident (50% occupancy). Each block: 256 threads = 16x16 pixels
// of one residue class, 6 of the 12 output timesteps. Thread: load x[12][4]
// once (float4/t), build X[57] = [x(t,c), A(c), D(c), 1], dot against <=4
// wave-uniform (scalar-load) packed weight slices per to.
__global__ __launch_bounds__(256, 4) void dlinear_main(const float* __restrict__ x,
                                                       const float* __restrict__ PW,
                                                       float* __restrict__ out) {
    int tid = threadIdx.x;
    int hh = tid >> 4;  // 0..15
    int ww = tid & 15;  // 0..15
    int tg = blockIdx.x & 1;          // to-group: to = 6*tg .. 6*tg+5
    int cls = (blockIdx.x >> 1) & 15; // residue class
    int bb = blockIdx.x >> 5;         // batch
    int rh = cls >> 2;  // h residue 0..3
    int rw = cls & 3;   // w residue 0..3
    int h = 4 * hh + rh;
    int w = 4 * ww + rw;

    // x layout (B,T,H,W,C): float4 index = (b*12+t)*4096 + h*64 + w
    const float4* xb = (const float4*)x + (size_t)bb * 12 * 4096 + h * 64 + w;

    float X[57];
    float sx = 0.f, sy = 0.f, sz = 0.f, sw = 0.f;
#pragma unroll
    for (int t = 0; t < 12; ++t) {
        float4 v = xb[t * 4096];
        X[t * 4 + 0] = v.x;
        X[t * 4 + 1] = v.y;
        X[t * 4 + 2] = v.z;
        X[t * 4 + 3] = v.w;
        sx += v.x; sy += v.y; sz += v.z; sw += v.w;
    }
    const float inv25 = 1.0f / 25.0f;
    {
        float S[4] = {sx, sy, sz, sw};
#pragma unroll
        for (int c = 0; c < 4; ++c) {
            float x0 = X[c], x11 = X[44 + c];
            X[48 + c] = (S[c] + 12.f * x0 + x11) * inv25;  // A
            X[52 + c] = (x11 - x0) * inv25;                // D
        }
    }
    X[56] = 1.0f;

    // combo validity: di=0 needs hh<=14; di=1 needs hh>=1 (same for j/ww)
    bool iv[2] = {hh <= 14, hh >= 1};
    bool jv[2] = {ww <= 14, ww >= 1};

    float4* ob = (float4*)out + (size_t)bb * 12 * 4096 + h * 64 + w;

#pragma unroll
    for (int tt = 0; tt < 6; ++tt) {
        int to = 6 * tg + tt;
        float rx = 0.f, ry = 0.f, rz = 0.f, rw4 = 0.f;
#pragma unroll
        for (int di = 0; di < 2; ++di) {
#pragma unroll
            for (int dj = 0; dj < 2; ++dj) {
                if (iv[di] && jv[dj]) {
                    int s = (rh + 4 * di) * 8 + (rw + 4 * dj);
                    const float* wb = PW + (size_t)(s * 48 + to * 4) * 64;
                    float a0 = 0.f, a1 = 0.f, a2 = 0.f, a3 = 0.f;
#pragma unroll
                    for (int k = 0; k < 57; ++k) {
                        float xv = X[k];
                        a0 += xv * wb[k];
                        a1 += xv * wb[64 + k];
                        a2 += xv * wb[128 + k];
                        a3 += xv * wb[192 + k];
                    }
                    rx += a0; ry += a1; rz += a2; rw4 += a3;
                }
            }
        }
        float4 r;
        r.x = rx; r.y = ry; r.z = rz; r.w = rw4;
        ob[to * 4096] = r;
    }
}

extern "C" void kernel_launch(void* const* d_in, const int* in_sizes, int n_in,
                              void* d_out, int out_size, void* d_ws, size_t ws_size,
                              hipStream_t stream) {
    const float* x = (const float*)d_in[0];
    const float* w_s = (const float*)d_in[1];
    const float* b_s = (const float*)d_in[2];
    const float* w_t = (const float*)d_in[3];
    const float* b_t = (const float*)d_in[4];
    float* out = (float*)d_out;
    float* PW = (float*)d_ws;  // needs 48*64*64*4 = 786432 bytes

    pack_weights<<<48, 64, 0, stream>>>(w_s, b_s, w_t, b_t, PW);
    dlinear_main<<<32 * 16 * 2, 256, 0, stream>>>(x, PW, out);
}